// Round 10
// baseline (320.972 us; speedup 1.0000x reference)
//
#include <hip/hip_runtime.h>
#include <stdint.h>

// dims
#define BB 512
#define SS 64
#define HH 1024
#define EE 256
#define VV 128

typedef __attribute__((ext_vector_type(8))) short bf16x8;
typedef __attribute__((ext_vector_type(4))) float f32x4;
typedef __attribute__((ext_vector_type(8))) unsigned short u16x8;

// ---- workspace layout (bytes, all 256-aligned) ----
constexpr size_t OFF_SCRATCH = 0;                         // 64MB scratch (gate partial-1)
constexpr size_t OFF_OUTW  = OFF_SCRATCH + 67108864UL;    // 128x1024 bf16
constexpr size_t OFF_HID0  = OFF_OUTW  + 262144UL;        // 512x1024 bf16 (input hidden[0])
constexpr size_t OFF_HLAST = OFF_HID0  + 1048576UL;       // 512x1024 bf16 (input hidden[1])
constexpr size_t OFF_UT    = OFF_HLAST + 1048576UL;       // 1024x1024 bf16 (U^T)
constexpr size_t OFF_WT    = OFF_UT    + 2097152UL;       // 1024x1024 bf16 (W^T)
constexpr size_t OFF_T2    = OFF_WT    + 2097152UL;       // 512x1024 f32
constexpr size_t OFF_E     = OFF_T2    + 2097152UL;       // 512x64 f32
constexpr size_t OFF_EMB   = OFF_E     + 131072UL;        // 512x256 bf16
constexpr size_t OFF_CT    = OFF_EMB   + 262144UL;        // 512x1024 bf16
constexpr size_t OFF_G     = OFF_CT    + 1048576UL;       // 512x4096 f32 (gate partial-0)
constexpr size_t OFF_H0B   = OFF_G     + 8388608UL;       // 512x1024 bf16
constexpr size_t OFF_H1B   = OFF_H0B   + 1048576UL;       // 512x1024 bf16

__device__ __forceinline__ unsigned short f2bf(float f) {
  unsigned int u = __float_as_uint(f);
  unsigned int r = (u + 0x7FFFu + ((u >> 16) & 1u)) >> 16;
  return (unsigned short)r;
}
__device__ __forceinline__ float bf2f(unsigned short h) {
  return __uint_as_float(((unsigned int)h) << 16);
}
// pack two f32 -> (bf16(a) | bf16(b)<<16), truncating; one v_perm_b32
__device__ __forceinline__ unsigned int pkbf(float a, float b) {
  return __builtin_amdgcn_perm(__float_as_uint(b), __float_as_uint(a), 0x07060302u);
}

__device__ __forceinline__ void gload_lds16(const void* g, void* l) {
  __builtin_amdgcn_global_load_lds(
      (const __attribute__((address_space(1))) unsigned int*)g,
      (__attribute__((address_space(3))) unsigned int*)l, 16, 0, 0);
}

// ---------------- small conversions: hid (both layers, contiguous) + out_w ----------------
__global__ __launch_bounds__(256) void cvt_small(const float* __restrict__ hid,
                                                 const float* __restrict__ outw,
                                                 char* __restrict__ ws) {
  int i = blockIdx.x * 256 + threadIdx.x;  // 294912 float4 units
  const float4* src;
  ushort4* dst;
  int j;
  if (i < 262144) { src = (const float4*)hid;  dst = (ushort4*)(ws + OFF_HID0); j = i; }
  else            { src = (const float4*)outw; dst = (ushort4*)(ws + OFF_OUTW); j = i - 262144; }
  float4 v = src[j];
  ushort4 o;
  o.x = f2bf(v.x); o.y = f2bf(v.y); o.z = f2bf(v.z); o.w = f2bf(v.w);
  dst[j] = o;
}

// ---------------- transpose-convert U and W (z selects) ----------------
__global__ void transpose_cvt2(const float* __restrict__ U, const float* __restrict__ W,
                               char* __restrict__ ws) {
  __shared__ float tile[32][33];
  const float* in = blockIdx.z ? W : U;
  unsigned short* out = (unsigned short*)(ws + (blockIdx.z ? OFF_WT : OFF_UT));
  int bc = blockIdx.x * 32, br = blockIdx.y * 32;
  int tx = threadIdx.x & 31, ty = threadIdx.x >> 5;
#pragma unroll
  for (int i = 0; i < 32; i += 8)
    tile[ty + i][tx] = in[(long)(br + ty + i) * HH + bc + tx];
  __syncthreads();
#pragma unroll
  for (int i = 0; i < 32; i += 8)
    out[(long)(bc + ty + i) * HH + br + tx] = f2bf(tile[tx][ty + i]);
}

// ---------------- embedded token gather -> bf16 ----------------
__global__ void build_xemb(const int* __restrict__ ids, const float* __restrict__ emb,
                           unsigned short* __restrict__ embb) {
  int t = blockIdx.x * 256 + threadIdx.x;  // 32768 float4s
  int b = t >> 6, c4 = t & 63;
  float4 v = ((const float4*)(emb + (long)ids[b] * 256))[c4];
  ushort4 o;
  o.x = f2bf(v.x); o.y = f2bf(v.y); o.z = f2bf(v.z); o.w = f2bf(v.w);
  ((ushort4*)embb)[t] = o;
}

// ---------------- segmented bf16 GEMM, split-K; B either bf16 (gload_lds) or f32 (reg-cvt) ----
template <int BF32>
__global__ __launch_bounds__(256) void gemm_seg(
    const unsigned short* __restrict__ A0, int KA0,
    const unsigned short* __restrict__ A1, int KA1,
    const unsigned short* __restrict__ A2,
    const void* __restrict__ B0v, int KB0, const void* __restrict__ B1v,
    float* __restrict__ C0p, float* __restrict__ C1p, int N, int Ktot, int Khalf) {
  __shared__ alignas(128) unsigned short lA[128 * 64];
  __shared__ alignas(128) unsigned short lB[64 * 64];
  const int tid = threadIdx.x;
  const int lane = tid & 63, wid = tid >> 6;
  const int wr = wid >> 1, wc = wid & 1;
  const int fr = lane & 15, fg = lane >> 4;
  f32x4 acc[4][2] = {};
  const long rowA0 = (long)blockIdx.x * 128;
  const long rowB0 = (long)blockIdx.y * 64;
  const int ktb = blockIdx.z * Khalf;
  int kte = ktb + Khalf; if (kte > Ktot) kte = Ktot;
  float* C = blockIdx.z ? C1p : C0p;
  for (int kt = ktb; kt < kte; kt += 64) {
    const unsigned short* Ap; int ka, lda;
    if (kt < KA0)            { Ap = A0; ka = kt;             lda = KA0; }
    else if (kt < KA0 + KA1) { Ap = A1; ka = kt - KA0;       lda = KA1; }
    else                     { Ap = A2; ka = kt - KA0 - KA1; lda = 1024; }
    if constexpr (BF32) {
      const float* Bp; int kb, ldb;
      if (kt < KB0) { Bp = (const float*)B0v; kb = kt;       ldb = KB0; }
      else          { Bp = (const float*)B1v; kb = kt - KB0; ldb = 1024; }
      const int brow = tid >> 2, bkq = tid & 3;
      const f32x4* bs = (const f32x4*)(Bp + (rowB0 + brow) * (long)ldb + kb) + bkq * 4;
      f32x4 q0 = bs[0], q1 = bs[1], q2 = bs[2], q3 = bs[3];
#pragma unroll
      for (int j = 0; j < 4; ++j) {
        int c = j * 256 + tid;
        int r = c >> 3, cc = c & 7;
        int sc = cc ^ ((r >> 1) & 7);
        gload_lds16(Ap + (rowA0 + r) * (long)lda + ka + sc * 8, &lA[c * 8]);
      }
      const int bx = (brow >> 1) & 7;
      uint4 w0, w1;
      w0.x = pkbf(q0[0], q0[1]); w0.y = pkbf(q0[2], q0[3]);
      w0.z = pkbf(q1[0], q1[1]); w0.w = pkbf(q1[2], q1[3]);
      w1.x = pkbf(q2[0], q2[1]); w1.y = pkbf(q2[2], q2[3]);
      w1.z = pkbf(q3[0], q3[1]); w1.w = pkbf(q3[2], q3[3]);
      *(uint4*)&lB[brow * 64 + (((bkq * 2) ^ bx) * 8)] = w0;
      *(uint4*)&lB[brow * 64 + (((bkq * 2 + 1) ^ bx) * 8)] = w1;
    } else {
      const unsigned short* Bp; int kb, ldb;
      if (kt < KB0) { Bp = (const unsigned short*)B0v; kb = kt;       ldb = KB0; }
      else          { Bp = (const unsigned short*)B1v; kb = kt - KB0; ldb = 1024; }
#pragma unroll
      for (int j = 0; j < 4; ++j) {
        int c = j * 256 + tid;
        int r = c >> 3, cc = c & 7;
        int sc = cc ^ ((r >> 1) & 7);
        gload_lds16(Ap + (rowA0 + r) * (long)lda + ka + sc * 8, &lA[c * 8]);
      }
#pragma unroll
      for (int j = 0; j < 2; ++j) {
        int c = j * 256 + tid;
        int r = c >> 3, cc = c & 7;
        int sc = cc ^ ((r >> 1) & 7);
        gload_lds16(Bp + (rowB0 + r) * (long)ldb + kb + sc * 8, &lB[c * 8]);
      }
    }
    __syncthreads();
#pragma unroll
    for (int kk = 0; kk < 64; kk += 32) {
      bf16x8 af[4], bfv[2];
#pragma unroll
      for (int m = 0; m < 4; ++m) {
        int row = wr * 64 + m * 16 + fr;
        int ch = ((kk >> 3) + fg) ^ ((row >> 1) & 7);
        af[m] = *(const bf16x8*)&lA[row * 64 + ch * 8];
      }
#pragma unroll
      for (int n = 0; n < 2; ++n) {
        int row = wc * 32 + n * 16 + fr;
        int ch = ((kk >> 3) + fg) ^ ((row >> 1) & 7);
        bfv[n] = *(const bf16x8*)&lB[row * 64 + ch * 8];
      }
#pragma unroll
      for (int m = 0; m < 4; ++m)
#pragma unroll
        for (int n = 0; n < 2; ++n)
          acc[m][n] = __builtin_amdgcn_mfma_f32_16x16x32_bf16(af[m], bfv[n],
                                                              acc[m][n], 0, 0, 0);
    }
    __syncthreads();
  }
#pragma unroll
  for (int m = 0; m < 4; ++m)
#pragma unroll
    for (int n = 0; n < 2; ++n)
#pragma unroll
      for (int r = 0; r < 4; ++r) {
        long grow = rowA0 + wr * 64 + m * 16 + fg * 4 + r;
        long gcol = rowB0 + wc * 32 + n * 16 + fr;
        C[grow * N + gcol] = acc[m][n][r];
      }
}

// ---------------- out projection, split-K, atomic accumulate ----------------
__global__ __launch_bounds__(256) void gemm_outproj(
    const unsigned short* __restrict__ A, const unsigned short* __restrict__ Bt,
    float* __restrict__ C) {
  __shared__ alignas(128) unsigned short lA[128 * 64];
  __shared__ alignas(128) unsigned short lB[128 * 64];
  const int tid = threadIdx.x;
  const int lane = tid & 63, wid = tid >> 6;
  const int wr = wid >> 1, wc = wid & 1;
  const int fr = lane & 15, fg = lane >> 4;
  f32x4 acc[4][4] = {};
  const long rowA0 = (long)blockIdx.x * 128;
  const int k0 = blockIdx.y * 128;
  for (int kt = k0; kt < k0 + 128; kt += 64) {
#pragma unroll
    for (int j = 0; j < 4; ++j) {
      int c = j * 256 + tid;
      int r = c >> 3, cc = c & 7;
      gload_lds16(A + (rowA0 + r) * 1024 + kt + cc * 8, &lA[c * 8]);
    }
#pragma unroll
    for (int j = 0; j < 4; ++j) {
      int c = j * 256 + tid;
      int r = c >> 3, cc = c & 7;
      gload_lds16(Bt + (long)r * 1024 + kt + cc * 8, &lB[c * 8]);
    }
    __syncthreads();
#pragma unroll
    for (int kk = 0; kk < 64; kk += 32) {
      bf16x8 af[4], bfv[4];
#pragma unroll
      for (int m = 0; m < 4; ++m)
        af[m] = *(const bf16x8*)&lA[(wr * 64 + m * 16 + fr) * 64 + kk + fg * 8];
#pragma unroll
      for (int n = 0; n < 4; ++n)
        bfv[n] = *(const bf16x8*)&lB[(wc * 64 + n * 16 + fr) * 64 + kk + fg * 8];
#pragma unroll
      for (int m = 0; m < 4; ++m)
#pragma unroll
        for (int n = 0; n < 4; ++n)
          acc[m][n] = __builtin_amdgcn_mfma_f32_16x16x32_bf16(af[m], bfv[n],
                                                              acc[m][n], 0, 0, 0);
    }
    __syncthreads();
  }
#pragma unroll
  for (int m = 0; m < 4; ++m)
#pragma unroll
    for (int n = 0; n < 4; ++n)
#pragma unroll
      for (int r = 0; r < 4; ++r) {
        long grow = rowA0 + wr * 64 + m * 16 + fg * 4 + r;
        long gcol = wc * 64 + n * 16 + fr;
        atomicAdd(&C[grow * 128 + gcol], acc[m][n][r]);
      }
}

__global__ void init_out_bias(const float* __restrict__ ob, float* __restrict__ out) {
  int i = blockIdx.x * 256 + threadIdx.x;
  out[i] = ob[i & 127];
}

// ---------------- 128x128 fused score GEMM (m97 structure, A = enc f32 on-the-fly) --------
// 256 thr (4 waves 2x2, wave tile 64x64), single-buffered 32 KB LDS, ~130 VGPR ->
// ~3 blocks/CU: inter-block overlap hides the staging (m97's proven mechanism).
// A: thread (arow=tid>>1, akh=tid&1) stages 32 floats of one row-khalf in 2 substages
// (16 regs live), pkbf pack (1 v_perm per pair). LDS lA[2kh][128][32], slot swizzle
// (s ^ ((arow>>1)&3) ^ akh)&3. B via gload_lds, 8-chunk swizzle (gemm_seg pattern).
__global__ __launch_bounds__(256) void gemm_score128f(
    const float* __restrict__ Af, const unsigned short* __restrict__ Bt,
    const float* __restrict__ t2, const float* __restrict__ Vw,
    float* __restrict__ e) {
  __shared__ alignas(128) unsigned short lA[8192];   // 16 KB
  __shared__ alignas(128) unsigned short lB[8192];   // 16 KB
  const int tid = threadIdx.x;
  const int lane = tid & 63, wid = tid >> 6;
  const int wr = wid >> 1, wc = wid & 1;
  const int fr = lane & 15, fg = lane >> 4;
  // XCD-chunked swizzle: 2048 blocks = 8 chunks x 256; nblk fastest within chunk.
  int flat = blockIdx.y * 8 + blockIdx.x;
  int swz = (flat & 7) * 256 + (flat >> 3);
  const long rowA0 = (long)(swz >> 3) * 128;   // enc row block (0..255)
  const long rowB0 = (long)(swz & 7) * 128;    // U^T row block (0..7)

  f32x4 acc[4][4] = {};

  const int arow = tid >> 1, akh = tid & 1;
  const float* ag = Af + (rowA0 + arow) * 1024 + akh * 32;
  const int awx = (arow >> 1) & 3;
  unsigned short* awb = lA + akh * 4096 + arow * 32;

  for (int kt = 0; kt < 16; ++kt) {
    // ---- stage B (4 x gload_lds) ----
#pragma unroll
    for (int j = 0; j < 4; ++j) {
      int c = j * 256 + tid;
      int r = c >> 3, cc = c & 7;
      int sc = cc ^ ((r >> 1) & 7);
      gload_lds16(Bt + (rowB0 + r) * 1024L + kt * 64 + sc * 8, &lB[c * 8]);
    }
    // ---- stage A: 2 substages of 4 f32x4 loads -> pkbf -> 2 x ds_write_b128 ----
    const f32x4* ap = (const f32x4*)(ag + kt * 64);
    {
      f32x4 q0 = ap[0], q1 = ap[1], q2 = ap[2], q3 = ap[3];
      uint4 w0, w1;
      w0.x = pkbf(q0[0], q0[1]); w0.y = pkbf(q0[2], q0[3]);
      w0.z = pkbf(q1[0], q1[1]); w0.w = pkbf(q1[2], q1[3]);
      w1.x = pkbf(q2[0], q2[1]); w1.y = pkbf(q2[2], q2[3]);
      w1.z = pkbf(q3[0], q3[1]); w1.w = pkbf(q3[2], q3[3]);
      *(uint4*)(awb + (((0 ^ awx ^ akh) & 3) * 8)) = w0;
      *(uint4*)(awb + (((1 ^ awx ^ akh) & 3) * 8)) = w1;
    }
    {
      f32x4 q0 = ap[4], q1 = ap[5], q2 = ap[6], q3 = ap[7];
      uint4 w0, w1;
      w0.x = pkbf(q0[0], q0[1]); w0.y = pkbf(q0[2], q0[3]);
      w0.z = pkbf(q1[0], q1[1]); w0.w = pkbf(q1[2], q1[3]);
      w1.x = pkbf(q2[0], q2[1]); w1.y = pkbf(q2[2], q2[3]);
      w1.z = pkbf(q3[0], q3[1]); w1.w = pkbf(q3[2], q3[3]);
      *(uint4*)(awb + (((2 ^ awx ^ akh) & 3) * 8)) = w0;
      *(uint4*)(awb + (((3 ^ awx ^ akh) & 3) * 8)) = w1;
    }
    __syncthreads();
    // ---- compute 32 MFMA ----
#pragma unroll
    for (int kk = 0; kk < 64; kk += 32) {
      const int kh = kk >> 5;
      bf16x8 af[4], bv[4];
#pragma unroll
      for (int m = 0; m < 4; ++m) {
        int row = wr * 64 + m * 16 + fr;
        int slot = (fg ^ ((row >> 1) & 3) ^ kh) & 3;
        af[m] = *(const bf16x8*)&lA[kh * 4096 + row * 32 + slot * 8];
      }
#pragma unroll
      for (int n = 0; n < 4; ++n) {
        int row = wc * 64 + n * 16 + fr;
        int ch = ((kk >> 3) + fg) ^ ((row >> 1) & 7);
        bv[n] = *(const bf16x8*)&lB[row * 64 + ch * 8];
      }
#pragma unroll
      for (int m = 0; m < 4; ++m)
#pragma unroll
        for (int n = 0; n < 4; ++n)
          acc[m][n] = __builtin_amdgcn_mfma_f32_16x16x32_bf16(af[m], bv[n],
                                                              acc[m][n], 0, 0, 0);
    }
    __syncthreads();
  }

  // ---- epilogue: e[row] += sum over this block's 128 cols of tanh(acc + t2) * Vw ----
  const long bidx = (rowA0 >> 6) + wr;      // wave M-half = exactly one batch row
  float t2v[4], vw[4];
#pragma unroll
  for (int n = 0; n < 4; ++n) {
    long col = rowB0 + wc * 64 + n * 16 + fr;
    vw[n] = Vw[col];
    t2v[n] = t2[bidx * HH + col];
  }
#pragma unroll
  for (int i = 0; i < 4; ++i) {
    float part[4] = {0.f, 0.f, 0.f, 0.f};
#pragma unroll
    for (int n = 0; n < 4; ++n) {
#pragma unroll
      for (int r = 0; r < 4; ++r) {
        float tval = acc[i][n][r] + t2v[n];
        float th = 1.f - 2.f / (__expf(2.f * tval) + 1.f);
        part[r] += th * vw[n];
      }
    }
#pragma unroll
    for (int r = 0; r < 4; ++r) {
      float p = part[r];
      p += __shfl_xor(p, 1);
      p += __shfl_xor(p, 2);
      p += __shfl_xor(p, 4);
      p += __shfl_xor(p, 8);
      if (fr == 0)
        atomicAdd(&e[rowA0 + wr * 64 + i * 16 + fg * 4 + r], p);
    }
  }
}

// ---------------- fused softmax (S=64) + context (reads enc f32, L3-warm) -> bf16 ----------
__global__ void softmax_ctx(const float* __restrict__ e,
                            const float* __restrict__ enc,
                            unsigned short* __restrict__ ctb) {
  __shared__ float als[2][64];
  const int tid = threadIdx.x;
  const int bpair = blockIdx.x;
  if (tid < 128) {
    int b = bpair * 2 + (tid >> 6), s = tid & 63;
    float v = e[b * 64 + s];
    float mx = v;
#pragma unroll
    for (int o = 32; o; o >>= 1) mx = fmaxf(mx, __shfl_xor(mx, o));
    float ex = __expf(v - mx);
    float sm = ex;
#pragma unroll
    for (int o = 32; o; o >>= 1) sm += __shfl_xor(sm, o);
    als[tid >> 6][s] = ex / sm;
  }
  __syncthreads();
  int bi = tid >> 7, hg = tid & 127;
  int b = bpair * 2 + bi;
  const float* er = enc + (long)b * (SS * HH) + hg * 8;
  float s[8] = {0.f, 0.f, 0.f, 0.f, 0.f, 0.f, 0.f, 0.f};
  for (int i = 0; i < 64; ++i) {
    float av = als[bi][i];
    f32x4 v0 = *(const f32x4*)(er + (long)i * HH);
    f32x4 v1 = *(const f32x4*)(er + (long)i * HH + 4);
#pragma unroll
    for (int j = 0; j < 4; ++j) { s[j] += av * v0[j]; s[4 + j] += av * v1[j]; }
  }
  unsigned short* dst = ctb + (long)b * HH + hg * 8;
#pragma unroll
  for (int j = 0; j < 8; ++j) dst[j] = f2bf(s[j]);
}

// ---------------- LSTM cell elementwise (sums two split-K partials) ----------------
__global__ void lstm_cell(const float* __restrict__ g0, const float* __restrict__ g1,
                          const float* __restrict__ bih, const float* __restrict__ bhh,
                          const float* __restrict__ cin,
                          float* __restrict__ hout, float* __restrict__ cout,
                          unsigned short* __restrict__ hb) {
  int idx = blockIdx.x * 256 + threadIdx.x;  // 512*1024
  int b = idx >> 10, h = idx & 1023;
  const float* gr0 = g0 + (long)b * 4096;
  const float* gr1 = g1 + (long)b * 4096;
  float gi = gr0[h] + gr1[h] + bih[h] + bhh[h];
  float gf = gr0[1024 + h] + gr1[1024 + h] + bih[1024 + h] + bhh[1024 + h];
  float gg = gr0[2048 + h] + gr1[2048 + h] + bih[2048 + h] + bhh[2048 + h];
  float go = gr0[3072 + h] + gr1[3072 + h] + bih[3072 + h] + bhh[3072 + h];
  float si = 1.f / (1.f + __expf(-gi));
  float sf = 1.f / (1.f + __expf(-gf));
  float so = 1.f / (1.f + __expf(-go));
  float tg = 1.f - 2.f / (__expf(2.f * gg) + 1.f);
  float c2 = sf * cin[idx] + si * tg;
  float tc = 1.f - 2.f / (__expf(2.f * c2) + 1.f);
  float h2 = so * tc;
  cout[idx] = c2;
  hout[idx] = h2;
  hb[idx] = f2bf(h2);
}

extern "C" void kernel_launch(void* const* d_in, const int* in_sizes, int n_in,
                              void* d_out, int out_size, void* d_ws, size_t ws_size,
                              hipStream_t stream) {
  const int* ids = (const int*)d_in[0];
  const float* hidden = (const float*)d_in[1];
  const float* cell = (const float*)d_in[2];
  const float* enc = (const float*)d_in[3];
  const float* emb = (const float*)d_in[4];
  const float* U = (const float*)d_in[5];
  const float* W = (const float*)d_in[6];
  const float* Vw = (const float*)d_in[7];
  const float* Wih0 = (const float*)d_in[8];
  const float* Whh0 = (const float*)d_in[9];
  const float* bih0 = (const float*)d_in[10];
  const float* bhh0 = (const float*)d_in[11];
  const float* Wih1 = (const float*)d_in[12];
  const float* Whh1 = (const float*)d_in[13];
  const float* bih1 = (const float*)d_in[14];
  const float* bhh1 = (const float*)d_in[15];
  const float* out_w = (const float*)d_in[16];
  const float* out_b = (const float*)d_in[17];
  float* out = (float*)d_out;
  char* ws = (char*)d_ws;
  (void)in_sizes; (void)n_in; (void)out_size; (void)ws_size;

  unsigned short* outwb  = (unsigned short*)(ws + OFF_OUTW);
  unsigned short* hid0b  = (unsigned short*)(ws + OFF_HID0);
  unsigned short* hlastb = (unsigned short*)(ws + OFF_HLAST);
  unsigned short* Utb    = (unsigned short*)(ws + OFF_UT);
  unsigned short* Wtb    = (unsigned short*)(ws + OFF_WT);
  float*          t2     = (float*)(ws + OFF_T2);
  float*          e      = (float*)(ws + OFF_E);
  unsigned short* embb   = (unsigned short*)(ws + OFF_EMB);
  unsigned short* ctb    = (unsigned short*)(ws + OFF_CT);
  float*          g      = (float*)(ws + OFF_G);
  float*          gB     = (float*)(ws + OFF_SCRATCH);
  unsigned short* h0b    = (unsigned short*)(ws + OFF_H0B);
  unsigned short* h1b    = (unsigned short*)(ws + OFF_H1B);

  float* out_logits = out;
  float* h_new = out + BB * VV;
  float* c_new = h_new + 2 * BB * HH;

  // ---- prep ----
  cvt_small<<<1152, 256, 0, stream>>>(hidden, out_w, ws);
  transpose_cvt2<<<dim3(32, 32, 2), 256, 0, stream>>>(U, W, ws);
  build_xemb<<<128, 256, 0, stream>>>(ids, emb, embb);
  hipMemsetAsync(e, 0, (size_t)BB * SS * 4, stream);

  // ---- t2 = hidden[1] @ W (B = Wt bf16) ----
  gemm_seg<0><<<dim3(4, 16, 1), 256, 0, stream>>>(hlastb, 1024, nullptr, 0, nullptr,
                                                  Wtb, 1024, nullptr, t2, t2, HH, 1024, 1024);

  // ---- scores e (A = enc f32 on-the-fly, 128x128 m97-style) ----
  gemm_score128f<<<dim3(8, 256), 256, 0, stream>>>(enc, Utb, t2, Vw, e);

  // ---- fused softmax + context (enc f32, L3-warm) ----
  softmax_ctx<<<256, 256, 0, stream>>>(e, enc, ctb);

  // ---- LSTM layer 0: g = [emb | ct | hid0] @ [Wih0 | Whh0]^T (weights f32) ----
  gemm_seg<1><<<dim3(4, 64, 2), 256, 0, stream>>>(embb, 256, ctb, 1024, hid0b,
                                                  Wih0, 1280, Whh0, g, gB, 4 * HH, 2304, 1152);
  lstm_cell<<<BB * HH / 256, 256, 0, stream>>>(g, gB, bih0, bhh0, cell, h_new, c_new, h0b);

  // ---- LSTM layer 1: g = [h0 | hid1] @ [Wih1 | Whh1]^T (weights f32) ----
  gemm_seg<1><<<dim3(4, 64, 2), 256, 0, stream>>>(h0b, 1024, hlastb, 1024, nullptr,
                                                  Wih1, 1024, Whh1, g, gB, 4 * HH, 2048, 1024);
  lstm_cell<<<BB * HH / 256, 256, 0, stream>>>(g, gB, bih1, bhh1, cell + BB * HH,
                                               h_new + BB * HH, c_new + BB * HH, h1b);

  // ---- output projection ----
  init_out_bias<<<BB * VV / 256, 256, 0, stream>>>(out_b, out_logits);
  gemm_outproj<<<dim3(4, 8), 256, 0, stream>>>(h1b, outwb, out_logits);
}

// Round 11
// 236.646 us; speedup vs baseline: 1.3563x; 1.3563x over previous
//
#include <hip/hip_runtime.h>
#include <stdint.h>

// dims
#define BB 512
#define SS 64
#define HH 1024
#define EE 256
#define VV 128

typedef __attribute__((ext_vector_type(8))) short bf16x8;
typedef __attribute__((ext_vector_type(4))) float f32x4;
typedef __attribute__((ext_vector_type(8))) unsigned short u16x8;

// ---- workspace layout (bytes, all 256-aligned) ----
constexpr size_t OFF_ENC   = 0;                           // 64MB enc bf16 (reused as gate partial-1 after softmax_ctx)
constexpr size_t OFF_OUTW  = OFF_ENC   + 67108864UL;      // 128x1024 bf16
constexpr size_t OFF_HID0  = OFF_OUTW  + 262144UL;        // 512x1024 bf16 (input hidden[0])
constexpr size_t OFF_HLAST = OFF_HID0  + 1048576UL;       // 512x1024 bf16 (input hidden[1])
constexpr size_t OFF_UT    = OFF_HLAST + 1048576UL;       // 1024x1024 bf16 (U^T)
constexpr size_t OFF_WT    = OFF_UT    + 2097152UL;       // 1024x1024 bf16 (W^T)
constexpr size_t OFF_T2    = OFF_WT    + 2097152UL;       // 512x1024 f32
constexpr size_t OFF_E     = OFF_T2    + 2097152UL;       // 512x64 f32
constexpr size_t OFF_EMB   = OFF_E     + 131072UL;        // 512x256 bf16
constexpr size_t OFF_CT    = OFF_EMB   + 262144UL;        // 512x1024 bf16
constexpr size_t OFF_G     = OFF_CT    + 1048576UL;       // 512x4096 f32 (gate partial-0)
constexpr size_t OFF_H0B   = OFF_G     + 8388608UL;       // 512x1024 bf16
constexpr size_t OFF_H1B   = OFF_H0B   + 1048576UL;       // 512x1024 bf16

__device__ __forceinline__ unsigned short f2bf(float f) {
  unsigned int u = __float_as_uint(f);
  unsigned int r = (u + 0x7FFFu + ((u >> 16) & 1u)) >> 16;
  return (unsigned short)r;
}
__device__ __forceinline__ float bf2f(unsigned short h) {
  return __uint_as_float(((unsigned int)h) << 16);
}
// pack two f32 -> (bf16(a) | bf16(b)<<16), truncating; one v_perm_b32
__device__ __forceinline__ unsigned int pkbf(float a, float b) {
  return __builtin_amdgcn_perm(__float_as_uint(b), __float_as_uint(a), 0x07060302u);
}

__device__ __forceinline__ void gload_lds16(const void* g, void* l) {
  __builtin_amdgcn_global_load_lds(
      (const __attribute__((address_space(1))) unsigned int*)g,
      (__attribute__((address_space(3))) unsigned int*)l, 16, 0, 0);
}

// ---------------- enc f32 -> bf16 (the only bulk conversion) ----------------
__global__ __launch_bounds__(256) void cvt_enc(const float* __restrict__ enc,
                                               unsigned short* __restrict__ encb) {
  long i = (long)blockIdx.x * 256 + threadIdx.x;  // 8388608 float4 units
  float4 v = ((const float4*)enc)[i];
  ushort4 o;
  o.x = f2bf(v.x); o.y = f2bf(v.y); o.z = f2bf(v.z); o.w = f2bf(v.w);
  ((ushort4*)encb)[i] = o;
}

// ---------------- small conversions: hid (both layers, contiguous) + out_w ----------------
__global__ __launch_bounds__(256) void cvt_small(const float* __restrict__ hid,
                                                 const float* __restrict__ outw,
                                                 char* __restrict__ ws) {
  int i = blockIdx.x * 256 + threadIdx.x;  // 294912 float4 units
  const float4* src;
  ushort4* dst;
  int j;
  if (i < 262144) { src = (const float4*)hid;  dst = (ushort4*)(ws + OFF_HID0); j = i; }
  else            { src = (const float4*)outw; dst = (ushort4*)(ws + OFF_OUTW); j = i - 262144; }
  float4 v = src[j];
  ushort4 o;
  o.x = f2bf(v.x); o.y = f2bf(v.y); o.z = f2bf(v.z); o.w = f2bf(v.w);
  dst[j] = o;
}

// ---------------- transpose-convert U and W (z selects) ----------------
__global__ void transpose_cvt2(const float* __restrict__ U, const float* __restrict__ W,
                               char* __restrict__ ws) {
  __shared__ float tile[32][33];
  const float* in = blockIdx.z ? W : U;
  unsigned short* out = (unsigned short*)(ws + (blockIdx.z ? OFF_WT : OFF_UT));
  int bc = blockIdx.x * 32, br = blockIdx.y * 32;
  int tx = threadIdx.x & 31, ty = threadIdx.x >> 5;
#pragma unroll
  for (int i = 0; i < 32; i += 8)
    tile[ty + i][tx] = in[(long)(br + ty + i) * HH + bc + tx];
  __syncthreads();
#pragma unroll
  for (int i = 0; i < 32; i += 8)
    out[(long)(bc + ty + i) * HH + br + tx] = f2bf(tile[tx][ty + i]);
}

// ---------------- embedded token gather -> bf16 ----------------
__global__ void build_xemb(const int* __restrict__ ids, const float* __restrict__ emb,
                           unsigned short* __restrict__ embb) {
  int t = blockIdx.x * 256 + threadIdx.x;  // 32768 float4s
  int b = t >> 6, c4 = t & 63;
  float4 v = ((const float4*)(emb + (long)ids[b] * 256))[c4];
  ushort4 o;
  o.x = f2bf(v.x); o.y = f2bf(v.y); o.z = f2bf(v.z); o.w = f2bf(v.w);
  ((ushort4*)embb)[t] = o;
}

// ---------------- segmented bf16 GEMM, split-K; B either bf16 (gload_lds) or f32 (reg-cvt) ----
template <int BF32>
__global__ __launch_bounds__(256) void gemm_seg(
    const unsigned short* __restrict__ A0, int KA0,
    const unsigned short* __restrict__ A1, int KA1,
    const unsigned short* __restrict__ A2,
    const void* __restrict__ B0v, int KB0, const void* __restrict__ B1v,
    float* __restrict__ C0p, float* __restrict__ C1p, int N, int Ktot, int Khalf) {
  __shared__ alignas(128) unsigned short lA[128 * 64];
  __shared__ alignas(128) unsigned short lB[64 * 64];
  const int tid = threadIdx.x;
  const int lane = tid & 63, wid = tid >> 6;
  const int wr = wid >> 1, wc = wid & 1;
  const int fr = lane & 15, fg = lane >> 4;
  f32x4 acc[4][2] = {};
  const long rowA0 = (long)blockIdx.x * 128;
  const long rowB0 = (long)blockIdx.y * 64;
  const int ktb = blockIdx.z * Khalf;
  int kte = ktb + Khalf; if (kte > Ktot) kte = Ktot;
  float* C = blockIdx.z ? C1p : C0p;
  for (int kt = ktb; kt < kte; kt += 64) {
    const unsigned short* Ap; int ka, lda;
    if (kt < KA0)            { Ap = A0; ka = kt;             lda = KA0; }
    else if (kt < KA0 + KA1) { Ap = A1; ka = kt - KA0;       lda = KA1; }
    else                     { Ap = A2; ka = kt - KA0 - KA1; lda = 1024; }
    if constexpr (BF32) {
      const float* Bp; int kb, ldb;
      if (kt < KB0) { Bp = (const float*)B0v; kb = kt;       ldb = KB0; }
      else          { Bp = (const float*)B1v; kb = kt - KB0; ldb = 1024; }
      const int brow = tid >> 2, bkq = tid & 3;
      const f32x4* bs = (const f32x4*)(Bp + (rowB0 + brow) * (long)ldb + kb) + bkq * 4;
      f32x4 q0 = bs[0], q1 = bs[1], q2 = bs[2], q3 = bs[3];
#pragma unroll
      for (int j = 0; j < 4; ++j) {
        int c = j * 256 + tid;
        int r = c >> 3, cc = c & 7;
        int sc = cc ^ ((r >> 1) & 7);
        gload_lds16(Ap + (rowA0 + r) * (long)lda + ka + sc * 8, &lA[c * 8]);
      }
      const int bx = (brow >> 1) & 7;
      uint4 w0, w1;
      w0.x = pkbf(q0[0], q0[1]); w0.y = pkbf(q0[2], q0[3]);
      w0.z = pkbf(q1[0], q1[1]); w0.w = pkbf(q1[2], q1[3]);
      w1.x = pkbf(q2[0], q2[1]); w1.y = pkbf(q2[2], q2[3]);
      w1.z = pkbf(q3[0], q3[1]); w1.w = pkbf(q3[2], q3[3]);
      *(uint4*)&lB[brow * 64 + (((bkq * 2) ^ bx) * 8)] = w0;
      *(uint4*)&lB[brow * 64 + (((bkq * 2 + 1) ^ bx) * 8)] = w1;
    } else {
      const unsigned short* Bp; int kb, ldb;
      if (kt < KB0) { Bp = (const unsigned short*)B0v; kb = kt;       ldb = KB0; }
      else          { Bp = (const unsigned short*)B1v; kb = kt - KB0; ldb = 1024; }
#pragma unroll
      for (int j = 0; j < 4; ++j) {
        int c = j * 256 + tid;
        int r = c >> 3, cc = c & 7;
        int sc = cc ^ ((r >> 1) & 7);
        gload_lds16(Ap + (rowA0 + r) * (long)lda + ka + sc * 8, &lA[c * 8]);
      }
#pragma unroll
      for (int j = 0; j < 2; ++j) {
        int c = j * 256 + tid;
        int r = c >> 3, cc = c & 7;
        int sc = cc ^ ((r >> 1) & 7);
        gload_lds16(Bp + (rowB0 + r) * (long)ldb + kb + sc * 8, &lB[c * 8]);
      }
    }
    __syncthreads();
#pragma unroll
    for (int kk = 0; kk < 64; kk += 32) {
      bf16x8 af[4], bfv[2];
#pragma unroll
      for (int m = 0; m < 4; ++m) {
        int row = wr * 64 + m * 16 + fr;
        int ch = ((kk >> 3) + fg) ^ ((row >> 1) & 7);
        af[m] = *(const bf16x8*)&lA[row * 64 + ch * 8];
      }
#pragma unroll
      for (int n = 0; n < 2; ++n) {
        int row = wc * 32 + n * 16 + fr;
        int ch = ((kk >> 3) + fg) ^ ((row >> 1) & 7);
        bfv[n] = *(const bf16x8*)&lB[row * 64 + ch * 8];
      }
#pragma unroll
      for (int m = 0; m < 4; ++m)
#pragma unroll
        for (int n = 0; n < 2; ++n)
          acc[m][n] = __builtin_amdgcn_mfma_f32_16x16x32_bf16(af[m], bfv[n],
                                                              acc[m][n], 0, 0, 0);
    }
    __syncthreads();
  }
#pragma unroll
  for (int m = 0; m < 4; ++m)
#pragma unroll
    for (int n = 0; n < 2; ++n)
#pragma unroll
      for (int r = 0; r < 4; ++r) {
        long grow = rowA0 + wr * 64 + m * 16 + fg * 4 + r;
        long gcol = rowB0 + wc * 32 + n * 16 + fr;
        C[grow * N + gcol] = acc[m][n][r];
      }
}

// ---------------- out projection, split-K, atomic accumulate ----------------
__global__ __launch_bounds__(256) void gemm_outproj(
    const unsigned short* __restrict__ A, const unsigned short* __restrict__ Bt,
    float* __restrict__ C) {
  __shared__ alignas(128) unsigned short lA[128 * 64];
  __shared__ alignas(128) unsigned short lB[128 * 64];
  const int tid = threadIdx.x;
  const int lane = tid & 63, wid = tid >> 6;
  const int wr = wid >> 1, wc = wid & 1;
  const int fr = lane & 15, fg = lane >> 4;
  f32x4 acc[4][4] = {};
  const long rowA0 = (long)blockIdx.x * 128;
  const int k0 = blockIdx.y * 128;
  for (int kt = k0; kt < k0 + 128; kt += 64) {
#pragma unroll
    for (int j = 0; j < 4; ++j) {
      int c = j * 256 + tid;
      int r = c >> 3, cc = c & 7;
      gload_lds16(A + (rowA0 + r) * 1024 + kt + cc * 8, &lA[c * 8]);
    }
#pragma unroll
    for (int j = 0; j < 4; ++j) {
      int c = j * 256 + tid;
      int r = c >> 3, cc = c & 7;
      gload_lds16(Bt + (long)r * 1024 + kt + cc * 8, &lB[c * 8]);
    }
    __syncthreads();
#pragma unroll
    for (int kk = 0; kk < 64; kk += 32) {
      bf16x8 af[4], bfv[4];
#pragma unroll
      for (int m = 0; m < 4; ++m)
        af[m] = *(const bf16x8*)&lA[(wr * 64 + m * 16 + fr) * 64 + kk + fg * 8];
#pragma unroll
      for (int n = 0; n < 4; ++n)
        bfv[n] = *(const bf16x8*)&lB[(wc * 64 + n * 16 + fr) * 64 + kk + fg * 8];
#pragma unroll
      for (int m = 0; m < 4; ++m)
#pragma unroll
        for (int n = 0; n < 4; ++n)
          acc[m][n] = __builtin_amdgcn_mfma_f32_16x16x32_bf16(af[m], bfv[n],
                                                              acc[m][n], 0, 0, 0);
    }
    __syncthreads();
  }
#pragma unroll
  for (int m = 0; m < 4; ++m)
#pragma unroll
    for (int n = 0; n < 4; ++n)
#pragma unroll
      for (int r = 0; r < 4; ++r) {
        long grow = rowA0 + wr * 64 + m * 16 + fg * 4 + r;
        long gcol = wc * 64 + n * 16 + fr;
        atomicAdd(&C[grow * 128 + gcol], acc[m][n][r]);
      }
}

__global__ void init_out_bias(const float* __restrict__ ob, float* __restrict__ out) {
  int i = blockIdx.x * 256 + threadIdx.x;
  out[i] = ob[i & 127];
}

// ---------------- 256x256 8-phase score GEMM (bf16 A), reg-prefetch + XCD swizzle ---------
// Verified r2-r6: ~95 us, MfmaUtil ~31%, bank conflicts 0.
__global__ __launch_bounds__(512, 2) void gemm_score256(
    const unsigned short* __restrict__ A, const unsigned short* __restrict__ Bt,
    const float* __restrict__ t2, const float* __restrict__ Vw,
    float* __restrict__ e) {
  extern __shared__ unsigned short smem[];  // [2][4][8192]
  const int K = HH;
  const int tid = threadIdx.x;
  const int lane = tid & 63, wid = tid >> 6;
  const int wr = wid >> 2;       // M half (128 rows)
  const int wcc = wid & 3;       // N quarter (64 cols)
  const int fr = lane & 15, fg = lane >> 4;
  int flat = blockIdx.y * 4 + blockIdx.x;
  int swz = (flat & 7) * 64 + (flat >> 3);     // XCD-chunked swizzle (512 = 8x64)
  const long rowA0 = (long)(swz >> 2) * 256;
  const long rowB0 = (long)(swz & 3) * 256;
  const int NKT = 16, NIT = 8;

  f32x4 acc[8][4] = {};

  auto RA = [&](int buf, int kh) { return (const unsigned short*)(smem + (buf * 4 + kh * 2) * 8192); };
  auto RB = [&](int buf, int kh) { return (const unsigned short*)(smem + (buf * 4 + kh * 2 + 1) * 8192); };

  auto stage = [&](int buf, int reg, int ktile) {
    const unsigned short* base = (reg & 1) ? Bt : A;
    long r0 = (reg & 1) ? rowB0 : rowA0;
    int kb = ktile * 64 + (reg >> 1) * 32;
    unsigned short* dst = smem + (buf * 4 + reg) * 8192;
#pragma unroll
    for (int j = 0; j < 2; ++j) {
      int c = j * 512 + tid;
      int row = c >> 2;
      int fgl = (c & 3) ^ ((row >> 1) & 3);
      gload_lds16(base + (r0 + row) * (long)K + kb + fgl * 8, dst + c * 8);
    }
  };
  auto readA = [&](const unsigned short* rg, int mh, bf16x8* af) {
#pragma unroll
    for (int m = 0; m < 4; ++m) {
      int row = wr * 128 + mh * 64 + m * 16 + fr;
      int slot = fg ^ ((row >> 1) & 3);
      af[m] = *(const bf16x8*)(rg + row * 32 + slot * 8);
    }
  };
  auto readB = [&](const unsigned short* rg, bf16x8* bv) {
#pragma unroll
    for (int n = 0; n < 4; ++n) {
      int row = wcc * 64 + n * 16 + fr;
      int slot = fg ^ ((row >> 1) & 3);
      bv[n] = *(const bf16x8*)(rg + row * 32 + slot * 8);
    }
  };
  auto mfma16 = [&](int mh, const bf16x8* af, const bf16x8* bv) {
    __builtin_amdgcn_s_setprio(1);
#pragma unroll
    for (int m = 0; m < 4; ++m)
#pragma unroll
      for (int n = 0; n < 4; ++n)
        acc[mh * 4 + m][n] = __builtin_amdgcn_mfma_f32_16x16x32_bf16(
            af[m], bv[n], acc[mh * 4 + m][n], 0, 0, 0);
    __builtin_amdgcn_s_setprio(0);
  };

#define BAR() __builtin_amdgcn_s_barrier()
#define WAIT6() asm volatile("s_waitcnt vmcnt(6)" ::: "memory")

  bf16x8 afA[4], afB[4], bvA[4], bvB[4];

  stage(0, 0, 0); stage(0, 1, 0); stage(0, 2, 0); stage(0, 3, 0);
  stage(1, 0, 1); stage(1, 1, 1);
  asm volatile("s_waitcnt vmcnt(8)" ::: "memory");
  BAR();
  readA(RA(0, 0), 0, afA); readB(RB(0, 0), bvA);

  for (int t = 0; t < NIT; ++t) {
    int k1 = 2 * t + 1, k2 = 2 * t + 2, k3 = 2 * t + 3;
    if (k2 >= NKT) k2 -= NKT;
    if (k3 >= NKT) k3 -= NKT;
    // p1
    readA(RA(0, 0), 1, afB);
    stage(1, 2, k1);
    BAR(); mfma16(0, afA, bvA); BAR();
    // p2
    WAIT6();
    readA(RA(0, 1), 0, afA); readB(RB(0, 1), bvB);
    stage(1, 3, k1);
    BAR(); mfma16(1, afB, bvA); BAR();
    // p3
    readA(RA(0, 1), 1, afB);
    stage(0, 0, k2);
    BAR(); mfma16(0, afA, bvB); BAR();
    // p4
    WAIT6();
    readA(RA(1, 0), 0, afA); readB(RB(1, 0), bvA);
    stage(0, 1, k2);
    BAR(); mfma16(1, afB, bvB); BAR();
    // p5
    readA(RA(1, 0), 1, afB);
    stage(0, 2, k2);
    BAR(); mfma16(0, afA, bvA); BAR();
    // p6
    WAIT6();
    readA(RA(1, 1), 0, afA); readB(RB(1, 1), bvB);
    stage(0, 3, k2);
    BAR(); mfma16(1, afB, bvA); BAR();
    // p7
    readA(RA(1, 1), 1, afB);
    stage(1, 0, k3);
    BAR(); mfma16(0, afA, bvB); BAR();
    // p8
    WAIT6();
    readA(RA(0, 0), 0, afA); readB(RB(0, 0), bvA);
    stage(1, 1, k3);
    BAR(); mfma16(1, afB, bvB); BAR();
  }
  asm volatile("s_waitcnt vmcnt(0)" ::: "memory");

  float t2v[2][4], vw[4];
#pragma unroll
  for (int n = 0; n < 4; ++n) {
    long col = rowB0 + wcc * 64 + n * 16 + fr;
    vw[n] = Vw[col];
#pragma unroll
    for (int h = 0; h < 2; ++h) {
      long b = (rowA0 >> 6) + wr * 2 + h;
      t2v[h][n] = t2[b * HH + col];
    }
  }
#pragma unroll
  for (int i = 0; i < 8; ++i) {
    int hsel = i >> 2;
    float part[4] = {0.f, 0.f, 0.f, 0.f};
#pragma unroll
    for (int n = 0; n < 4; ++n) {
#pragma unroll
      for (int r = 0; r < 4; ++r) {
        float tval = acc[i][n][r] + t2v[hsel][n];
        float th = 1.f - 2.f / (__expf(2.f * tval) + 1.f);
        part[r] += th * vw[n];
      }
    }
#pragma unroll
    for (int r = 0; r < 4; ++r) {
      float p = part[r];
      p += __shfl_xor(p, 1);
      p += __shfl_xor(p, 2);
      p += __shfl_xor(p, 4);
      p += __shfl_xor(p, 8);
      if (fr == 0)
        atomicAdd(&e[rowA0 + wr * 128 + i * 16 + fg * 4 + r], p);
    }
  }
#undef BAR
#undef WAIT6
}

// ---------------- fused softmax (S=64) + context (bf16 enc, L3-hot) -> bf16 ----------------
__global__ void softmax_ctx(const float* __restrict__ e,
                            const unsigned short* __restrict__ encb,
                            unsigned short* __restrict__ ctb) {
  __shared__ float als[2][64];
  const int tid = threadIdx.x;
  const int bpair = blockIdx.x;
  if (tid < 128) {
    int b = bpair * 2 + (tid >> 6), s = tid & 63;
    float v = e[b * 64 + s];
    float mx = v;
#pragma unroll
    for (int o = 32; o; o >>= 1) mx = fmaxf(mx, __shfl_xor(mx, o));
    float ex = __expf(v - mx);
    float sm = ex;
#pragma unroll
    for (int o = 32; o; o >>= 1) sm += __shfl_xor(sm, o);
    als[tid >> 6][s] = ex / sm;
  }
  __syncthreads();
  int bi = tid >> 7, hg = tid & 127;
  int b = bpair * 2 + bi;
  const unsigned short* er = encb + (long)b * (SS * HH) + hg * 8;
  float s[8] = {0.f, 0.f, 0.f, 0.f, 0.f, 0.f, 0.f, 0.f};
  for (int i = 0; i < 64; ++i) {
    float av = als[bi][i];
    bf16x8 v = *(const bf16x8*)(er + (long)i * HH);
#pragma unroll
    for (int j = 0; j < 8; ++j) s[j] += av * bf2f((unsigned short)v[j]);
  }
  unsigned short* dst = ctb + (long)b * HH + hg * 8;
#pragma unroll
  for (int j = 0; j < 8; ++j) dst[j] = f2bf(s[j]);
}

// ---------------- LSTM cell elementwise (sums two split-K partials) ----------------
__global__ void lstm_cell(const float* __restrict__ g0, const float* __restrict__ g1,
                          const float* __restrict__ bih, const float* __restrict__ bhh,
                          const float* __restrict__ cin,
                          float* __restrict__ hout, float* __restrict__ cout,
                          unsigned short* __restrict__ hb) {
  int idx = blockIdx.x * 256 + threadIdx.x;  // 512*1024
  int b = idx >> 10, h = idx & 1023;
  const float* gr0 = g0 + (long)b * 4096;
  const float* gr1 = g1 + (long)b * 4096;
  float gi = gr0[h] + gr1[h] + bih[h] + bhh[h];
  float gf = gr0[1024 + h] + gr1[1024 + h] + bih[1024 + h] + bhh[1024 + h];
  float gg = gr0[2048 + h] + gr1[2048 + h] + bih[2048 + h] + bhh[2048 + h];
  float go = gr0[3072 + h] + gr1[3072 + h] + bih[3072 + h] + bhh[3072 + h];
  float si = 1.f / (1.f + __expf(-gi));
  float sf = 1.f / (1.f + __expf(-gf));
  float so = 1.f / (1.f + __expf(-go));
  float tg = 1.f - 2.f / (__expf(2.f * gg) + 1.f);
  float c2 = sf * cin[idx] + si * tg;
  float tc = 1.f - 2.f / (__expf(2.f * c2) + 1.f);
  float h2 = so * tc;
  cout[idx] = c2;
  hout[idx] = h2;
  hb[idx] = f2bf(h2);
}

extern "C" void kernel_launch(void* const* d_in, const int* in_sizes, int n_in,
                              void* d_out, int out_size, void* d_ws, size_t ws_size,
                              hipStream_t stream) {
  const int* ids = (const int*)d_in[0];
  const float* hidden = (const float*)d_in[1];
  const float* cell = (const float*)d_in[2];
  const float* enc = (const float*)d_in[3];
  const float* emb = (const float*)d_in[4];
  const float* U = (const float*)d_in[5];
  const float* W = (const float*)d_in[6];
  const float* Vw = (const float*)d_in[7];
  const float* Wih0 = (const float*)d_in[8];
  const float* Whh0 = (const float*)d_in[9];
  const float* bih0 = (const float*)d_in[10];
  const float* bhh0 = (const float*)d_in[11];
  const float* Wih1 = (const float*)d_in[12];
  const float* Whh1 = (const float*)d_in[13];
  const float* bih1 = (const float*)d_in[14];
  const float* bhh1 = (const float*)d_in[15];
  const float* out_w = (const float*)d_in[16];
  const float* out_b = (const float*)d_in[17];
  float* out = (float*)d_out;
  char* ws = (char*)d_ws;
  (void)in_sizes; (void)n_in; (void)out_size; (void)ws_size;

  unsigned short* enc_b  = (unsigned short*)(ws + OFF_ENC);
  unsigned short* outwb  = (unsigned short*)(ws + OFF_OUTW);
  unsigned short* hid0b  = (unsigned short*)(ws + OFF_HID0);
  unsigned short* hlastb = (unsigned short*)(ws + OFF_HLAST);
  unsigned short* Utb    = (unsigned short*)(ws + OFF_UT);
  unsigned short* Wtb    = (unsigned short*)(ws + OFF_WT);
  float*          t2     = (float*)(ws + OFF_T2);
  float*          e      = (float*)(ws + OFF_E);
  unsigned short* embb   = (unsigned short*)(ws + OFF_EMB);
  unsigned short* ctb    = (unsigned short*)(ws + OFF_CT);
  float*          g      = (float*)(ws + OFF_G);
  float*          gB     = (float*)(ws + OFF_ENC);  // gate partial-1: aliases enc_b (dead after softmax_ctx)
  unsigned short* h0b    = (unsigned short*)(ws + OFF_H0B);
  unsigned short* h1b    = (unsigned short*)(ws + OFF_H1B);

  float* out_logits = out;
  float* h_new = out + BB * VV;
  float* c_new = h_new + 2 * BB * HH;

  // ---- prep: enc conversion (the only bulk one) + small conversions ----
  cvt_enc<<<32768, 256, 0, stream>>>(enc, enc_b);
  cvt_small<<<1152, 256, 0, stream>>>(hidden, out_w, ws);
  transpose_cvt2<<<dim3(32, 32, 2), 256, 0, stream>>>(U, W, ws);
  build_xemb<<<128, 256, 0, stream>>>(ids, emb, embb);
  hipMemsetAsync(e, 0, (size_t)BB * SS * 4, stream);

  // ---- t2 = hidden[1] @ W (B = Wt bf16) ----
  gemm_seg<0><<<dim3(4, 16, 1), 256, 0, stream>>>(hlastb, 1024, nullptr, 0, nullptr,
                                                  Wtb, 1024, nullptr, t2, t2, HH, 1024, 1024);

  // ---- scores e (bf16 8-phase 256^2, proven ~95 us) ----
  (void)hipFuncSetAttribute(reinterpret_cast<const void*>(gemm_score256),
                            hipFuncAttributeMaxDynamicSharedMemorySize, 131072);
  gemm_score256<<<dim3(4, 128), 512, 131072, stream>>>(enc_b, Utb, t2, Vw, e);

  // ---- fused softmax + context (bf16 enc, L3-hot) ----
  softmax_ctx<<<256, 256, 0, stream>>>(e, enc_b, ctb);

  // ---- LSTM layer 0: g = [emb | ct | hid0] @ [Wih0 | Whh0]^T (weights f32, fused cvt) ----
  gemm_seg<1><<<dim3(4, 64, 2), 256, 0, stream>>>(embb, 256, ctb, 1024, hid0b,
                                                  Wih0, 1280, Whh0, g, gB, 4 * HH, 2304, 1152);
  lstm_cell<<<BB * HH / 256, 256, 0, stream>>>(g, gB, bih0, bhh0, cell, h_new, c_new, h0b);

  // ---- LSTM layer 1: g = [h0 | hid1] @ [Wih1 | Whh1]^T (weights f32, fused cvt) ----
  gemm_seg<1><<<dim3(4, 64, 2), 256, 0, stream>>>(h0b, 1024, hlastb, 1024, nullptr,
                                                  Wih1, 1024, Whh1, g, gB, 4 * HH, 2048, 1024);
  lstm_cell<<<BB * HH / 256, 256, 0, stream>>>(g, gB, bih1, bhh1, cell + BB * HH,
                                               h_new + BB * HH, c_new + BB * HH, h1b);

  // ---- output projection ----
  init_out_bias<<<BB * VV / 256, 256, 0, stream>>>(out_b, out_logits);
  gemm_outproj<<<dim3(4, 8), 256, 0, stream>>>(h1b, outwb, out_logits);
}